// Round 17
// baseline (164.112 us; speedup 1.0000x reference)
//
#include <hip/hip_runtime.h>
#include <hip/hip_bf16.h>

#define Cc 64
#define Hc 128
#define Wc 128
#define HWc (Hc * Wc)
#define Bc 4

typedef __attribute__((ext_vector_type(8))) short short8;
typedef __attribute__((ext_vector_type(4))) float float4v;

static __device__ __forceinline__ unsigned short f2bu(float f) {
    __hip_bfloat16 h = __float2bfloat16(f);
    return *(unsigned short*)&h;
}
static __device__ __forceinline__ float bulo(unsigned int u) {
    return __uint_as_float((u & 0xffffu) << 16);
}
static __device__ __forceinline__ float buhi(unsigned int u) {
    return __uint_as_float(u & 0xffff0000u);
}

static __device__ __forceinline__ void gl_lds16(const void* g, void* l) {
    __builtin_amdgcn_global_load_lds(
        (const __attribute__((address_space(1))) unsigned int*)g,
        (__attribute__((address_space(3))) unsigned int*)l, 16, 0, 0);
}

// ---------------------------------------------------------------------------
// prep: blocks 0..511 cvt, 512..587 weight pack, 588 zpage zero.
// ---------------------------------------------------------------------------
__global__ __launch_bounds__(256) void prep_k(
    const float* __restrict__ x, const float* __restrict__ kf,
    const float* __restrict__ fw1, const float* __restrict__ fw2,
    const float* __restrict__ mw1, const float* __restrict__ mw2,
    const float* __restrict__ lw1, const float* __restrict__ lw2,
    unsigned short* __restrict__ xb, unsigned short* __restrict__ kfb,
    unsigned short* __restrict__ wbase, unsigned short* __restrict__ zpage)
{
    const int bid = blockIdx.x;
    const int tid = threadIdx.x;

    if (bid < 512) {
        const bool isx = bid < 256;
        const float* src = isx ? x : kf;
        unsigned short* dst = isx ? xb : kfb;
        const int px = (isx ? bid : bid - 256) * 256 + tid;
        const int b  = px >> 14;
        const int hw = px & 16383;
        const float* s = src + (size_t)b * Cc * HWc + hw;
        unsigned short* d = dst + (size_t)px * Cc;
#pragma unroll
        for (int c8 = 0; c8 < 8; ++c8) {
            unsigned int pk[4];
#pragma unroll
            for (int jp = 0; jp < 4; ++jp) {
                float v0 = s[(size_t)(c8 * 8 + jp * 2 + 0) * HWc];
                float v1 = s[(size_t)(c8 * 8 + jp * 2 + 1) * HWc];
                if (isx) { v0 = fmaxf(v0, 0.f); v1 = fmaxf(v1, 0.f); }
                pk[jp] = (unsigned int)f2bu(v0) | ((unsigned int)f2bu(v1) << 16);
            }
            *(uint4*)(d + c8 * 8) = make_uint4(pk[0], pk[1], pk[2], pk[3]);
        }
    } else if (bid < 584) {
        const int wbid  = bid - 512;
        const int which = wbid / 18;
        const float* w = (which == 0) ? fw1 : (which == 1) ? fw2 : (which == 2) ? mw1 : mw2;
        unsigned short* wb = wbase + (size_t)which * 36864;
        const int g = (wbid % 18) * 256 + tid;
        if (g >= 4608) return;
        const int lane = g & 63;
        const int smt  = g >> 6;
        const int s    = smt >> 2;
        const int mt   = smt & 3;
        const int co   = mt * 16 + (lane & 15);
        const int kb   = s * 32 + (lane >> 4) * 8;
        unsigned int pk[4];
#pragma unroll
        for (int jp = 0; jp < 4; ++jp) {
            int k0 = kb + jp * 2, k1 = k0 + 1;
            float v0 = w[((size_t)co * Cc + (k0 & 63)) * 9 + (k0 >> 6)];
            float v1 = w[((size_t)co * Cc + (k1 & 63)) * 9 + (k1 >> 6)];
            pk[jp] = (unsigned int)f2bu(v0) | ((unsigned int)f2bu(v1) << 16);
        }
        *(uint4*)(wb + (size_t)g * 8) = make_uint4(pk[0], pk[1], pk[2], pk[3]);
    } else if (bid < 588) {
        const int wbid  = bid - 584;
        const int which = wbid >> 1;
        const float* w = which ? lw2 : lw1;
        const int Cout = which ? 49 : 64;
        unsigned short* wb = wbase + 4 * 36864 + (size_t)which * 4096;
        const int g = (wbid & 1) * 256 + tid;
        const int lane = g & 63;
        const int smt  = g >> 6;
        const int s    = smt >> 2;
        const int mt   = smt & 3;
        const int co   = mt * 16 + (lane & 15);
        const int kb   = s * 32 + (lane >> 4) * 8;
        unsigned int pk[4];
#pragma unroll
        for (int jp = 0; jp < 4; ++jp) {
            int k0 = kb + jp * 2, k1 = k0 + 1;
            float v0 = (co < Cout) ? w[(size_t)co * Cc + k0] : 0.f;
            float v1 = (co < Cout) ? w[(size_t)co * Cc + k1] : 0.f;
            pk[jp] = (unsigned int)f2bu(v0) | ((unsigned int)f2bu(v1) << 16);
        }
        *(uint4*)(wb + (size_t)g * 8) = make_uint4(pk[0], pk[1], pk[2], pk[3]);
    } else {
        if (tid < 64) ((unsigned int*)zpage)[tid] = 0;
    }
}

// ===== staging (async DMA, swizzle via lane->channel permutation) ==========
#define STAGE_DMA(INPTR, SBUF)                                                \
    for (int k = wv; k < 33; k += 4) {                                        \
        const int u_  = k * 8 + (lane >> 3);                                  \
        const int j_  = lane & 7;                                             \
        const int r_  = u_ / 66;                                              \
        const int c_  = u_ - r_ * 66;                                         \
        const int gh_ = h0 - 1 + r_;                                          \
        const int gw_ = w0 - 1 + c_;                                          \
        const bool ok_ = ((unsigned)gh_ < (unsigned)Hc) && ((unsigned)gw_ < (unsigned)Wc); \
        const int ch_ = j_ ^ (u_ & 7);                                        \
        const unsigned short* g_ = ok_                                        \
            ? (INPTR) + ((((size_t)b * Hc + gh_) * Wc + gw_) << 6) + (ch_ << 3) \
            : zpage + (ch_ << 3);                                             \
        gl_lds16(g_, &(SBUF)[k * 512]);                                       \
    }

#define LOAD_A(W, s, m) (*(const short8*)((W) + (size_t)(s) * 2048 + (size_t)(m) * 512))
#define LOAD_B(SB, s, nt) ({                                                  \
        const int tap_ = (s) >> 1;                                            \
        const int qb_  = rowb[tap_ / 3] + tap_ % 3;                           \
        const int ch0_ = ((s) & 1) * 4 + quad;                                \
        *(const short8*)&(SB)[(qb_ + (nt) * 16) * 64 + ((ch0_ ^ (qb_ & 7)) << 3)]; })

// Software-pipelined GEMM. A: ring of 4, prefetch distance 3.
// B: explicit depth-1 cur/nxt.
#define CONV_GEMM(APTR, ACC, SB)                                              \
    {                                                                         \
        short8 a_buf[4][2], b_cur[4], b_nxt[4];                               \
        _Pragma("unroll")                                                     \
        for (int q = 0; q < 3; ++q)                                           \
            _Pragma("unroll")                                                 \
            for (int m = 0; m < 2; ++m) a_buf[q][m] = LOAD_A(APTR, q, m);     \
        _Pragma("unroll")                                                     \
        for (int nt = 0; nt < 4; ++nt) b_cur[nt] = LOAD_B(SB, 0, nt);         \
        _Pragma("unroll")                                                     \
        for (int s = 0; s < 18; ++s) {                                        \
            if (s + 3 < 18) {                                                 \
                _Pragma("unroll")                                             \
                for (int m = 0; m < 2; ++m)                                   \
                    a_buf[(s + 3) & 3][m] = LOAD_A(APTR, s + 3, m);           \
            }                                                                 \
            if (s + 1 < 18) {                                                 \
                _Pragma("unroll")                                             \
                for (int nt = 0; nt < 4; ++nt)                                \
                    b_nxt[nt] = LOAD_B(SB, s + 1, nt);                        \
            }                                                                 \
            _Pragma("unroll")                                                 \
            for (int nt = 0; nt < 4; ++nt)                                    \
                _Pragma("unroll")                                             \
                for (int m = 0; m < 2; ++m)                                   \
                    ACC[m][nt] = __builtin_amdgcn_mfma_f32_16x16x32_bf16(     \
                        a_buf[s & 3][m], b_cur[nt], ACC[m][nt], 0, 0, 0);     \
            if (s + 1 < 18) {                                                 \
                _Pragma("unroll")                                             \
                for (int nt = 0; nt < 4; ++nt) b_cur[nt] = b_nxt[nt];         \
            }                                                                 \
        }                                                                     \
    }

// ---------------------------------------------------------------------------
// conv1 + lp merged, 2-row tiles, producer-aligned XCD map (round-16 best).
// ---------------------------------------------------------------------------
__global__ __launch_bounds__(256) void conv1_lp_k(
    const unsigned short* __restrict__ in0,
    const unsigned short* __restrict__ in1,
    const unsigned short* __restrict__ wfrag0,
    const unsigned short* __restrict__ wfrag1,
    const float* __restrict__ bias0,
    const float* __restrict__ bias1,
    const unsigned short* __restrict__ zpage,
    unsigned short* __restrict__ out0,
    unsigned short* __restrict__ out1,
    const unsigned short* __restrict__ w1, const float* __restrict__ b1,
    const unsigned short* __restrict__ w2, const float* __restrict__ b2,
    unsigned short* __restrict__ lpout)
{
    __shared__ unsigned short s_b[264 * 64];

    const int tid  = threadIdx.x;
    const int lane = tid & 63;
    const int wv   = tid >> 6;
    const int quad = lane >> 4;
    const int glin = blockIdx.x;
    const int xcd  = glin & 7;
    const int slot = glin >> 3;

    if (slot < 128) {
        const int sel = slot >> 6;
        const int hti = slot & 63;
        const int b   = xcd >> 1;
        const int w0  = (xcd & 1) * 64;
        const int h0  = hti * 2;

        const unsigned short* in    = sel ? in1 : in0;
        const unsigned short* wfrag = sel ? wfrag1 : wfrag0;
        const float*          bias  = sel ? bias1 : bias0;
        unsigned short*       out   = sel ? out1 : out0;

        STAGE_DMA(in, s_b);
        __syncthreads();

        const int rowsel = wv >> 1;
        const int cohalf = wv & 1;
        const int n15    = lane & 15;
        const unsigned short* aptr = wfrag + (((size_t)(cohalf * 2) * 64 + lane) << 3);

        int rowb[3];
#pragma unroll
        for (int ky = 0; ky < 3; ++ky) rowb[ky] = (rowsel + ky) * 66 + n15;

        float4v acc[2][4];
#pragma unroll
        for (int m = 0; m < 2; ++m)
#pragma unroll
            for (int nt = 0; nt < 4; ++nt) acc[m][nt] = (float4v){0.f, 0.f, 0.f, 0.f};

        CONV_GEMM(aptr, acc, s_b);

        const int h = h0 + rowsel;
#pragma unroll
        for (int m = 0; m < 2; ++m) {
            const int mt  = cohalf * 2 + m;
            const int co0 = mt * 16 + quad * 4;
            float4 bv = *(const float4*)&bias[co0];
#pragma unroll
            for (int nt = 0; nt < 4; ++nt) {
                const size_t pix = ((size_t)b * Hc + h) * Wc + w0 + nt * 16 + n15;
                ushort4 pk;
                pk.x = f2bu(fmaxf(acc[m][nt][0] + bv.x, 0.f));
                pk.y = f2bu(fmaxf(acc[m][nt][1] + bv.y, 0.f));
                pk.z = f2bu(fmaxf(acc[m][nt][2] + bv.z, 0.f));
                pk.w = f2bu(fmaxf(acc[m][nt][3] + bv.w, 0.f));
                *(ushort4*)&out[pix * Cc + co0] = pk;
            }
        }
    } else {
        const int lpid = xcd * 128 + (slot - 128);
        const int p    = lane & 15;
        const size_t pix = (size_t)lpid * 64 + wv * 16 + p;
        unsigned short* st = &s_b[wv * 1024];

        float4v acc1[4];
#pragma unroll
        for (int mt = 0; mt < 4; ++mt) acc1[mt] = (float4v){0.f, 0.f, 0.f, 0.f};
#pragma unroll
        for (int s = 0; s < 2; ++s) {
            short8 bfr = *(const short8*)&in1[pix * Cc + s * 32 + quad * 8];
#pragma unroll
            for (int mt = 0; mt < 4; ++mt) {
                short8 afr = *(const short8*)&w1[(size_t)(((s * 4 + mt) << 6) + lane) << 3];
                acc1[mt] = __builtin_amdgcn_mfma_f32_16x16x32_bf16(afr, bfr, acc1[mt], 0, 0, 0);
            }
        }

#pragma unroll
        for (int mt = 0; mt < 4; ++mt) {
            const int co0 = mt * 16 + quad * 4;
            float4 bv = *(const float4*)&b1[co0];
            ushort4 pk;
            pk.x = f2bu(fmaxf(acc1[mt][0] + bv.x, 0.f));
            pk.y = f2bu(fmaxf(acc1[mt][1] + bv.y, 0.f));
            pk.z = f2bu(fmaxf(acc1[mt][2] + bv.z, 0.f));
            pk.w = f2bu(fmaxf(acc1[mt][3] + bv.w, 0.f));
            const int cg = co0 >> 3;
            *(ushort4*)&st[p * 64 + ((cg ^ (p & 7)) << 3) + (quad & 1) * 4] = pk;
        }
        __syncthreads();

        float4v acc2[4];
#pragma unroll
        for (int mt = 0; mt < 4; ++mt) acc2[mt] = (float4v){0.f, 0.f, 0.f, 0.f};
#pragma unroll
        for (int s = 0; s < 2; ++s) {
            const int cg = s * 4 + quad;
            short8 bfr = *(const short8*)&st[p * 64 + ((cg ^ (p & 7)) << 3)];
#pragma unroll
            for (int mt = 0; mt < 4; ++mt) {
                short8 afr = *(const short8*)&w2[(size_t)(((s * 4 + mt) << 6) + lane) << 3];
                acc2[mt] = __builtin_amdgcn_mfma_f32_16x16x32_bf16(afr, bfr, acc2[mt], 0, 0, 0);
            }
        }

        float v[4][4];
        float partial = 0.f;
#pragma unroll
        for (int mt = 0; mt < 4; ++mt) {
#pragma unroll
            for (int r = 0; r < 4; ++r) {
                const int tap = mt * 16 + quad * 4 + r;
                float val = (tap < 49) ? (acc2[mt][r] + b2[tap]) : 0.f;
                v[mt][r] = val;
                partial += val;
            }
        }
        partial += __shfl_xor(partial, 16, 64);
        partial += __shfl_xor(partial, 32, 64);
        const float m = partial * (1.f / 49.f) - (1.f / 49.f);

        const int b  = (int)(pix >> 14);
        const int hw = (int)(pix & 16383);
#pragma unroll
        for (int mt = 0; mt < 4; ++mt) {
#pragma unroll
            for (int r = 0; r < 4; ++r) {
                const int tap = mt * 16 + quad * 4 + r;
                if (tap < 49)
                    lpout[((size_t)b * 49 + tap) * HWc + hw] = f2bu(v[mt][r] - m);
            }
        }
    }
}

// ---------------------------------------------------------------------------
// conv2 fused, single-buffer SERIAL RESTAGE: 33.8 KB LDS -> 4 blocks/CU
// (vs round-16's 67.6 KB double-buffer at 2 blocks/CU). Phases:
// stage-f / GEMM-f (fp bf16-rounded into regs) / restage-m / GEMM-m /
// feat = fp*mp -> bf16 NCHW planes. Cross-block overlap hides the
// serialized DMA. Producer-aligned XCD map kept. grid = 512 (1-D).
// ---------------------------------------------------------------------------
__global__ __launch_bounds__(256) void conv2_fused_k(
    const unsigned short* __restrict__ t1f,
    const unsigned short* __restrict__ t1m,
    const unsigned short* __restrict__ wf,
    const unsigned short* __restrict__ wm,
    const float* __restrict__ bf,
    const float* __restrict__ bm,
    const unsigned short* __restrict__ zpage,
    unsigned short* __restrict__ featp)
{
    __shared__ unsigned short s_b[264 * 64];

    const int tid  = threadIdx.x;
    const int lane = tid & 63;
    const int wv   = tid >> 6;
    const int glin = blockIdx.x;
    const int xcd  = glin & 7;
    const int slot = glin >> 3;          // 0..63
    const int b    = xcd >> 1;
    const int w0   = (xcd & 1) * 64;
    const int h0   = slot * 2;

    const int rowsel = wv >> 1;
    const int cohalf = wv & 1;
    const int quad   = lane >> 4;
    const int n15    = lane & 15;

    int rowb[3];
#pragma unroll
    for (int ky = 0; ky < 3; ++ky) rowb[ky] = (rowsel + ky) * 66 + n15;

    // ---- phase A: feature conv2 ----
    STAGE_DMA(t1f, s_b);
    __syncthreads();

    float4v acc[2][4];
#pragma unroll
    for (int m = 0; m < 2; ++m)
#pragma unroll
        for (int nt = 0; nt < 4; ++nt) acc[m][nt] = (float4v){0.f, 0.f, 0.f, 0.f};

    {
        const unsigned short* aptr = wf + (((size_t)(cohalf * 2) * 64 + lane) << 3);
        CONV_GEMM(aptr, acc, s_b);
    }

    float fpv[2][4][4];
#pragma unroll
    for (int m = 0; m < 2; ++m) {
        const int mt  = cohalf * 2 + m;
        const int co0 = mt * 16 + quad * 4;
        float4 bv = *(const float4*)&bf[co0];
#pragma unroll
        for (int nt = 0; nt < 4; ++nt) {
            fpv[m][nt][0] = bulo((unsigned int)f2bu(acc[m][nt][0] + bv.x));
            fpv[m][nt][1] = bulo((unsigned int)f2bu(acc[m][nt][1] + bv.y));
            fpv[m][nt][2] = bulo((unsigned int)f2bu(acc[m][nt][2] + bv.z));
            fpv[m][nt][3] = bulo((unsigned int)f2bu(acc[m][nt][3] + bv.w));
        }
    }

    __syncthreads();   // all phase-A LDS reads complete before restage

    // ---- phase B: multiplicative conv2 ----
    STAGE_DMA(t1m, s_b);
    __syncthreads();

#pragma unroll
    for (int m = 0; m < 2; ++m)
#pragma unroll
        for (int nt = 0; nt < 4; ++nt) acc[m][nt] = (float4v){0.f, 0.f, 0.f, 0.f};

    {
        const unsigned short* aptr = wm + (((size_t)(cohalf * 2) * 64 + lane) << 3);
        CONV_GEMM(aptr, acc, s_b);
    }

    const int h = h0 + rowsel;
#pragma unroll
    for (int m = 0; m < 2; ++m) {
        const int mt  = cohalf * 2 + m;
        const int co0 = mt * 16 + quad * 4;
        float4 bv = *(const float4*)&bm[co0];
#pragma unroll
        for (int nt = 0; nt < 4; ++nt) {
            const int px = h * Wc + w0 + nt * 16 + n15;
            float v[4] = {acc[m][nt][0] + bv.x, acc[m][nt][1] + bv.y,
                          acc[m][nt][2] + bv.z, acc[m][nt][3] + bv.w};
#pragma unroll
            for (int r = 0; r < 4; ++r)
                featp[((size_t)b * Cc + co0 + r) * HWc + px] =
                    f2bu(v[r] * fpv[m][nt][r]);
        }
    }
}

// ---------------------------------------------------------------------------
// Dynamic local 7x7 conv + residual (round-14/16 version, unchanged).
// ---------------------------------------------------------------------------
__global__ __launch_bounds__(256) void local_conv_v4(
    const float* __restrict__ x, const unsigned short* __restrict__ featp,
    const unsigned short* __restrict__ lp, float* __restrict__ out)
{
    const int tid  = threadIdx.x;
    const int glin = blockIdx.x;
    const int xcd  = glin & 7;
    const int slot = glin >> 3;              // 0..127
    const int pair = xcd * 8 + (slot >> 4);  // 0..63
    const int cg   = slot & 15;
    const int b    = pair >> 4;
    const int hti  = pair & 15;

    const int w4  = (tid & 31) * 4;
    const int ro  = tid >> 5;
    const int h   = hti * 8 + ro;
    const int c0  = cg * 4;

    float msk[12];
#pragma unroll
    for (int e = 0; e < 12; ++e) {
        int gw = w4 - 4 + e;
        msk[e] = ((unsigned)gw < (unsigned)Wc) ? 1.f : 0.f;
    }

    float acc[4][4];
#pragma unroll
    for (int ch = 0; ch < 4; ++ch)
#pragma unroll
        for (int p = 0; p < 4; ++p) acc[ch][p] = 0.f;

    const unsigned short* lpb = lp + (size_t)b * 49 * HWc + (size_t)h * Wc + w4;
    const unsigned short* fb  = featp + ((size_t)b * Cc + c0) * HWc;

#pragma unroll
    for (int dy = 0; dy < 7; ++dy) {
        const int gh = h + dy - 3;
        if ((unsigned)gh >= (unsigned)Hc) continue;

        float lpf[7][4];
#pragma unroll
        for (int dx = 0; dx < 7; ++dx) {
            uint2 lv = *(const uint2*)&lpb[(size_t)(dy * 7 + dx) * HWc];
            lpf[dx][0] = bulo(lv.x); lpf[dx][1] = buhi(lv.x);
            lpf[dx][2] = bulo(lv.y); lpf[dx][3] = buhi(lv.y);
        }

        const unsigned short* frow = fb + (size_t)gh * Wc + w4;
#pragma unroll
        for (int ch = 0; ch < 4; ++ch) {
            const unsigned short* fr = frow + (size_t)ch * HWc;
            uint2 a  = *(const uint2*)(fr - 4);
            uint2 bq = *(const uint2*)(fr);
            uint2 cq = *(const uint2*)(fr + 4);
            float f[12];
            f[0]  = bulo(a.x);             f[1]  = buhi(a.x) * msk[1];
            f[2]  = bulo(a.y) * msk[2];    f[3]  = buhi(a.y) * msk[3];
            f[4]  = bulo(bq.x);            f[5]  = buhi(bq.x);
            f[6]  = bulo(bq.y);            f[7]  = buhi(bq.y);
            f[8]  = bulo(cq.x) * msk[8];   f[9]  = buhi(cq.x) * msk[9];
            f[10] = bulo(cq.y) * msk[10];  f[11] = buhi(cq.y);
#pragma unroll
            for (int dx = 0; dx < 7; ++dx)
#pragma unroll
                for (int p = 0; p < 4; ++p)
                    acc[ch][p] = fmaf(f[p + dx + 1], lpf[dx][p], acc[ch][p]);
        }
    }

#pragma unroll
    for (int ch = 0; ch < 4; ++ch) {
        const size_t idx = ((size_t)b * Cc + c0 + ch) * HWc + (size_t)h * Wc + w4;
        float4 xv = *(const float4*)&x[idx];
        float4 r  = {acc[ch][0] + xv.x, acc[ch][1] + xv.y,
                     acc[ch][2] + xv.z, acc[ch][3] + xv.w};
        *(float4*)&out[idx] = r;
    }
}

// ---------------------------------------------------------------------------
extern "C" void kernel_launch(void* const* d_in, const int* in_sizes, int n_in,
                              void* d_out, int out_size, void* d_ws, size_t ws_size,
                              hipStream_t stream)
{
    const float* x   = (const float*)d_in[0];
    const float* kf  = (const float*)d_in[1];
    const float* fw1 = (const float*)d_in[2];
    const float* fb1 = (const float*)d_in[3];
    const float* fw2 = (const float*)d_in[4];
    const float* fb2 = (const float*)d_in[5];
    const float* mw1 = (const float*)d_in[6];
    const float* mb1 = (const float*)d_in[7];
    const float* mw2 = (const float*)d_in[8];
    const float* mb2 = (const float*)d_in[9];
    const float* lw1 = (const float*)d_in[10];
    const float* lb1 = (const float*)d_in[11];
    const float* lw2 = (const float*)d_in[12];
    const float* lb2 = (const float*)d_in[13];

    float* out = (float*)d_out;
    char*  ws  = (char*)d_ws;

    const size_t NBH = (size_t)Bc * HWc * Cc * 2;   // bf16 tensor: 8.4 MB
    const size_t LPH = (size_t)Bc * 49 * HWc * 2;   // bf16 lp planes: 6.4 MB
    const size_t WBA = (size_t)(4 * 36864 + 2 * 4096) * 2;

    unsigned short* t1f   = (unsigned short*)(ws);
    unsigned short* t1m   = (unsigned short*)(ws + NBH);
    unsigned short* featp = (unsigned short*)(ws + 2 * NBH);
    unsigned short* lpb   = (unsigned short*)(ws + 3 * NBH);
    unsigned short* xb    = (unsigned short*)(ws + 3 * NBH + LPH);
    unsigned short* kfb   = (unsigned short*)((char*)xb + NBH);
    unsigned short* wbase = (unsigned short*)((char*)kfb + NBH);
    unsigned short* zpage = (unsigned short*)((char*)wbase + WBA);
    unsigned short* wb1   = wbase;
    unsigned short* wb2   = wbase + 36864;
    unsigned short* wb3   = wbase + 2 * 36864;
    unsigned short* wb4   = wbase + 3 * 36864;
    unsigned short* wl1   = wbase + 4 * 36864;
    unsigned short* wl2   = wbase + 4 * 36864 + 4096;

    dim3 blk(256);

    prep_k<<<dim3(589), blk, 0, stream>>>(x, kf, fw1, fw2, mw1, mw2, lw1, lw2,
                                          xb, kfb, wbase, zpage);

    conv1_lp_k<<<dim3(2048), blk, 0, stream>>>(xb, kfb, wb1, wb3, fb1, mb1, zpage,
                                               t1f, t1m, wl1, lb1, wl2, lb2, lpb);

    conv2_fused_k<<<dim3(512), blk, 0, stream>>>(t1f, t1m, wb2, wb4, fb2, mb2,
                                                 zpage, featp);

    local_conv_v4<<<dim3(1024), blk, 0, stream>>>(x, featp, lpb, out);
}

// Round 18
// 160.854 us; speedup vs baseline: 1.0203x; 1.0203x over previous
//
#include <hip/hip_runtime.h>
#include <hip/hip_bf16.h>

#define Cc 64
#define Hc 128
#define Wc 128
#define HWc (Hc * Wc)
#define Bc 4

typedef __attribute__((ext_vector_type(8))) short short8;
typedef __attribute__((ext_vector_type(4))) float float4v;

static __device__ __forceinline__ unsigned short f2bu(float f) {
    __hip_bfloat16 h = __float2bfloat16(f);
    return *(unsigned short*)&h;
}
static __device__ __forceinline__ float bulo(unsigned int u) {
    return __uint_as_float((u & 0xffffu) << 16);
}
static __device__ __forceinline__ float buhi(unsigned int u) {
    return __uint_as_float(u & 0xffff0000u);
}

static __device__ __forceinline__ void gl_lds16(const void* g, void* l) {
    __builtin_amdgcn_global_load_lds(
        (const __attribute__((address_space(1))) unsigned int*)g,
        (__attribute__((address_space(3))) unsigned int*)l, 16, 0, 0);
}

// ---------------------------------------------------------------------------
// prep: blocks 0..511 cvt, 512..587 weight pack, 588 zpage zero.
// ---------------------------------------------------------------------------
__global__ __launch_bounds__(256) void prep_k(
    const float* __restrict__ x, const float* __restrict__ kf,
    const float* __restrict__ fw1, const float* __restrict__ fw2,
    const float* __restrict__ mw1, const float* __restrict__ mw2,
    const float* __restrict__ lw1, const float* __restrict__ lw2,
    unsigned short* __restrict__ xb, unsigned short* __restrict__ kfb,
    unsigned short* __restrict__ wbase, unsigned short* __restrict__ zpage)
{
    const int bid = blockIdx.x;
    const int tid = threadIdx.x;

    if (bid < 512) {
        const bool isx = bid < 256;
        const float* src = isx ? x : kf;
        unsigned short* dst = isx ? xb : kfb;
        const int px = (isx ? bid : bid - 256) * 256 + tid;
        const int b  = px >> 14;
        const int hw = px & 16383;
        const float* s = src + (size_t)b * Cc * HWc + hw;
        unsigned short* d = dst + (size_t)px * Cc;
#pragma unroll
        for (int c8 = 0; c8 < 8; ++c8) {
            unsigned int pk[4];
#pragma unroll
            for (int jp = 0; jp < 4; ++jp) {
                float v0 = s[(size_t)(c8 * 8 + jp * 2 + 0) * HWc];
                float v1 = s[(size_t)(c8 * 8 + jp * 2 + 1) * HWc];
                if (isx) { v0 = fmaxf(v0, 0.f); v1 = fmaxf(v1, 0.f); }
                pk[jp] = (unsigned int)f2bu(v0) | ((unsigned int)f2bu(v1) << 16);
            }
            *(uint4*)(d + c8 * 8) = make_uint4(pk[0], pk[1], pk[2], pk[3]);
        }
    } else if (bid < 584) {
        const int wbid  = bid - 512;
        const int which = wbid / 18;
        const float* w = (which == 0) ? fw1 : (which == 1) ? fw2 : (which == 2) ? mw1 : mw2;
        unsigned short* wb = wbase + (size_t)which * 36864;
        const int g = (wbid % 18) * 256 + tid;
        if (g >= 4608) return;
        const int lane = g & 63;
        const int smt  = g >> 6;
        const int s    = smt >> 2;
        const int mt   = smt & 3;
        const int co   = mt * 16 + (lane & 15);
        const int kb   = s * 32 + (lane >> 4) * 8;
        unsigned int pk[4];
#pragma unroll
        for (int jp = 0; jp < 4; ++jp) {
            int k0 = kb + jp * 2, k1 = k0 + 1;
            float v0 = w[((size_t)co * Cc + (k0 & 63)) * 9 + (k0 >> 6)];
            float v1 = w[((size_t)co * Cc + (k1 & 63)) * 9 + (k1 >> 6)];
            pk[jp] = (unsigned int)f2bu(v0) | ((unsigned int)f2bu(v1) << 16);
        }
        *(uint4*)(wb + (size_t)g * 8) = make_uint4(pk[0], pk[1], pk[2], pk[3]);
    } else if (bid < 588) {
        const int wbid  = bid - 584;
        const int which = wbid >> 1;
        const float* w = which ? lw2 : lw1;
        const int Cout = which ? 49 : 64;
        unsigned short* wb = wbase + 4 * 36864 + (size_t)which * 4096;
        const int g = (wbid & 1) * 256 + tid;
        const int lane = g & 63;
        const int smt  = g >> 6;
        const int s    = smt >> 2;
        const int mt   = smt & 3;
        const int co   = mt * 16 + (lane & 15);
        const int kb   = s * 32 + (lane >> 4) * 8;
        unsigned int pk[4];
#pragma unroll
        for (int jp = 0; jp < 4; ++jp) {
            int k0 = kb + jp * 2, k1 = k0 + 1;
            float v0 = (co < Cout) ? w[(size_t)co * Cc + k0] : 0.f;
            float v1 = (co < Cout) ? w[(size_t)co * Cc + k1] : 0.f;
            pk[jp] = (unsigned int)f2bu(v0) | ((unsigned int)f2bu(v1) << 16);
        }
        *(uint4*)(wb + (size_t)g * 8) = make_uint4(pk[0], pk[1], pk[2], pk[3]);
    } else {
        if (tid < 64) ((unsigned int*)zpage)[tid] = 0;
    }
}

// ===== staging (async DMA, swizzle via lane->channel permutation) ==========
#define STAGE_DMA(INPTR, SBUF)                                                \
    for (int k = wv; k < 33; k += 4) {                                        \
        const int u_  = k * 8 + (lane >> 3);                                  \
        const int j_  = lane & 7;                                             \
        const int r_  = u_ / 66;                                              \
        const int c_  = u_ - r_ * 66;                                         \
        const int gh_ = h0 - 1 + r_;                                          \
        const int gw_ = w0 - 1 + c_;                                          \
        const bool ok_ = ((unsigned)gh_ < (unsigned)Hc) && ((unsigned)gw_ < (unsigned)Wc); \
        const int ch_ = j_ ^ (u_ & 7);                                        \
        const unsigned short* g_ = ok_                                        \
            ? (INPTR) + ((((size_t)b * Hc + gh_) * Wc + gw_) << 6) + (ch_ << 3) \
            : zpage + (ch_ << 3);                                             \
        gl_lds16(g_, &(SBUF)[k * 512]);                                       \
    }

#define LOAD_A(W, s, m) (*(const short8*)((W) + (size_t)(s) * 2048 + (size_t)(m) * 512))
#define LOAD_B(SB, s, nt) ({                                                  \
        const int tap_ = (s) >> 1;                                            \
        const int qb_  = rowb[tap_ / 3] + tap_ % 3;                           \
        const int ch0_ = ((s) & 1) * 4 + quad;                                \
        *(const short8*)&(SB)[(qb_ + (nt) * 16) * 64 + ((ch0_ ^ (qb_ & 7)) << 3)]; })

// Software-pipelined GEMM. A: ring of 4, prefetch distance 3.
// B: explicit depth-1 cur/nxt.
#define CONV_GEMM(APTR, ACC, SB)                                              \
    {                                                                         \
        short8 a_buf[4][2], b_cur[4], b_nxt[4];                               \
        _Pragma("unroll")                                                     \
        for (int q = 0; q < 3; ++q)                                           \
            _Pragma("unroll")                                                 \
            for (int m = 0; m < 2; ++m) a_buf[q][m] = LOAD_A(APTR, q, m);     \
        _Pragma("unroll")                                                     \
        for (int nt = 0; nt < 4; ++nt) b_cur[nt] = LOAD_B(SB, 0, nt);         \
        _Pragma("unroll")                                                     \
        for (int s = 0; s < 18; ++s) {                                        \
            if (s + 3 < 18) {                                                 \
                _Pragma("unroll")                                             \
                for (int m = 0; m < 2; ++m)                                   \
                    a_buf[(s + 3) & 3][m] = LOAD_A(APTR, s + 3, m);           \
            }                                                                 \
            if (s + 1 < 18) {                                                 \
                _Pragma("unroll")                                             \
                for (int nt = 0; nt < 4; ++nt)                                \
                    b_nxt[nt] = LOAD_B(SB, s + 1, nt);                        \
            }                                                                 \
            _Pragma("unroll")                                                 \
            for (int nt = 0; nt < 4; ++nt)                                    \
                _Pragma("unroll")                                             \
                for (int m = 0; m < 2; ++m)                                   \
                    ACC[m][nt] = __builtin_amdgcn_mfma_f32_16x16x32_bf16(     \
                        a_buf[s & 3][m], b_cur[nt], ACC[m][nt], 0, 0, 0);     \
            if (s + 1 < 18) {                                                 \
                _Pragma("unroll")                                             \
                for (int nt = 0; nt < 4; ++nt) b_cur[nt] = b_nxt[nt];         \
            }                                                                 \
        }                                                                     \
    }

// ---------------------------------------------------------------------------
// conv1 + lp merged, 2-row tiles, producer-aligned XCD map (round-16 best).
// ---------------------------------------------------------------------------
__global__ __launch_bounds__(256) void conv1_lp_k(
    const unsigned short* __restrict__ in0,
    const unsigned short* __restrict__ in1,
    const unsigned short* __restrict__ wfrag0,
    const unsigned short* __restrict__ wfrag1,
    const float* __restrict__ bias0,
    const float* __restrict__ bias1,
    const unsigned short* __restrict__ zpage,
    unsigned short* __restrict__ out0,
    unsigned short* __restrict__ out1,
    const unsigned short* __restrict__ w1, const float* __restrict__ b1,
    const unsigned short* __restrict__ w2, const float* __restrict__ b2,
    unsigned short* __restrict__ lpout)
{
    __shared__ unsigned short s_b[264 * 64];

    const int tid  = threadIdx.x;
    const int lane = tid & 63;
    const int wv   = tid >> 6;
    const int quad = lane >> 4;
    const int glin = blockIdx.x;
    const int xcd  = glin & 7;
    const int slot = glin >> 3;

    if (slot < 128) {
        const int sel = slot >> 6;
        const int hti = slot & 63;
        const int b   = xcd >> 1;
        const int w0  = (xcd & 1) * 64;
        const int h0  = hti * 2;

        const unsigned short* in    = sel ? in1 : in0;
        const unsigned short* wfrag = sel ? wfrag1 : wfrag0;
        const float*          bias  = sel ? bias1 : bias0;
        unsigned short*       out   = sel ? out1 : out0;

        STAGE_DMA(in, s_b);
        __syncthreads();

        const int rowsel = wv >> 1;
        const int cohalf = wv & 1;
        const int n15    = lane & 15;
        const unsigned short* aptr = wfrag + (((size_t)(cohalf * 2) * 64 + lane) << 3);

        int rowb[3];
#pragma unroll
        for (int ky = 0; ky < 3; ++ky) rowb[ky] = (rowsel + ky) * 66 + n15;

        float4v acc[2][4];
#pragma unroll
        for (int m = 0; m < 2; ++m)
#pragma unroll
            for (int nt = 0; nt < 4; ++nt) acc[m][nt] = (float4v){0.f, 0.f, 0.f, 0.f};

        CONV_GEMM(aptr, acc, s_b);

        const int h = h0 + rowsel;
#pragma unroll
        for (int m = 0; m < 2; ++m) {
            const int mt  = cohalf * 2 + m;
            const int co0 = mt * 16 + quad * 4;
            float4 bv = *(const float4*)&bias[co0];
#pragma unroll
            for (int nt = 0; nt < 4; ++nt) {
                const size_t pix = ((size_t)b * Hc + h) * Wc + w0 + nt * 16 + n15;
                ushort4 pk;
                pk.x = f2bu(fmaxf(acc[m][nt][0] + bv.x, 0.f));
                pk.y = f2bu(fmaxf(acc[m][nt][1] + bv.y, 0.f));
                pk.z = f2bu(fmaxf(acc[m][nt][2] + bv.z, 0.f));
                pk.w = f2bu(fmaxf(acc[m][nt][3] + bv.w, 0.f));
                *(ushort4*)&out[pix * Cc + co0] = pk;
            }
        }
    } else {
        const int lpid = xcd * 128 + (slot - 128);
        const int p    = lane & 15;
        const size_t pix = (size_t)lpid * 64 + wv * 16 + p;
        unsigned short* st = &s_b[wv * 1024];

        float4v acc1[4];
#pragma unroll
        for (int mt = 0; mt < 4; ++mt) acc1[mt] = (float4v){0.f, 0.f, 0.f, 0.f};
#pragma unroll
        for (int s = 0; s < 2; ++s) {
            short8 bfr = *(const short8*)&in1[pix * Cc + s * 32 + quad * 8];
#pragma unroll
            for (int mt = 0; mt < 4; ++mt) {
                short8 afr = *(const short8*)&w1[(size_t)(((s * 4 + mt) << 6) + lane) << 3];
                acc1[mt] = __builtin_amdgcn_mfma_f32_16x16x32_bf16(afr, bfr, acc1[mt], 0, 0, 0);
            }
        }

#pragma unroll
        for (int mt = 0; mt < 4; ++mt) {
            const int co0 = mt * 16 + quad * 4;
            float4 bv = *(const float4*)&b1[co0];
            ushort4 pk;
            pk.x = f2bu(fmaxf(acc1[mt][0] + bv.x, 0.f));
            pk.y = f2bu(fmaxf(acc1[mt][1] + bv.y, 0.f));
            pk.z = f2bu(fmaxf(acc1[mt][2] + bv.z, 0.f));
            pk.w = f2bu(fmaxf(acc1[mt][3] + bv.w, 0.f));
            const int cg = co0 >> 3;
            *(ushort4*)&st[p * 64 + ((cg ^ (p & 7)) << 3) + (quad & 1) * 4] = pk;
        }
        __syncthreads();

        float4v acc2[4];
#pragma unroll
        for (int mt = 0; mt < 4; ++mt) acc2[mt] = (float4v){0.f, 0.f, 0.f, 0.f};
#pragma unroll
        for (int s = 0; s < 2; ++s) {
            const int cg = s * 4 + quad;
            short8 bfr = *(const short8*)&st[p * 64 + ((cg ^ (p & 7)) << 3)];
#pragma unroll
            for (int mt = 0; mt < 4; ++mt) {
                short8 afr = *(const short8*)&w2[(size_t)(((s * 4 + mt) << 6) + lane) << 3];
                acc2[mt] = __builtin_amdgcn_mfma_f32_16x16x32_bf16(afr, bfr, acc2[mt], 0, 0, 0);
            }
        }

        float v[4][4];
        float partial = 0.f;
#pragma unroll
        for (int mt = 0; mt < 4; ++mt) {
#pragma unroll
            for (int r = 0; r < 4; ++r) {
                const int tap = mt * 16 + quad * 4 + r;
                float val = (tap < 49) ? (acc2[mt][r] + b2[tap]) : 0.f;
                v[mt][r] = val;
                partial += val;
            }
        }
        partial += __shfl_xor(partial, 16, 64);
        partial += __shfl_xor(partial, 32, 64);
        const float m = partial * (1.f / 49.f) - (1.f / 49.f);

        const int b  = (int)(pix >> 14);
        const int hw = (int)(pix & 16383);
#pragma unroll
        for (int mt = 0; mt < 4; ++mt) {
#pragma unroll
            for (int r = 0; r < 4; ++r) {
                const int tap = mt * 16 + quad * 4 + r;
                if (tap < 49)
                    lpout[((size_t)b * 49 + tap) * HWc + hw] = f2bu(v[mt][r] - m);
            }
        }
    }
}

// ---------------------------------------------------------------------------
// conv2 fused (round-16 best): BOTH tiles DMA'd up-front into double LDS,
// ONE barrier, two GEMMs, feat = fp*mp -> bf16 NCHW planes.
// Producer-aligned XCD map. grid = 512 (1-D).
// ---------------------------------------------------------------------------
__global__ __launch_bounds__(256) void conv2_fused_k(
    const unsigned short* __restrict__ t1f,
    const unsigned short* __restrict__ t1m,
    const unsigned short* __restrict__ wf,
    const unsigned short* __restrict__ wm,
    const float* __restrict__ bf,
    const float* __restrict__ bm,
    const unsigned short* __restrict__ zpage,
    unsigned short* __restrict__ featp)
{
    __shared__ unsigned short s_b2[2][264 * 64];

    const int tid  = threadIdx.x;
    const int lane = tid & 63;
    const int wv   = tid >> 6;
    const int glin = blockIdx.x;
    const int xcd  = glin & 7;
    const int slot = glin >> 3;          // 0..63
    const int b    = xcd >> 1;
    const int w0   = (xcd & 1) * 64;
    const int h0   = slot * 2;

    STAGE_DMA(t1f, s_b2[0]);
    STAGE_DMA(t1m, s_b2[1]);
    __syncthreads();

    const int rowsel = wv >> 1;
    const int cohalf = wv & 1;
    const int quad   = lane >> 4;
    const int n15    = lane & 15;

    int rowb[3];
#pragma unroll
    for (int ky = 0; ky < 3; ++ky) rowb[ky] = (rowsel + ky) * 66 + n15;

    float4v acc[2][4];
#pragma unroll
    for (int m = 0; m < 2; ++m)
#pragma unroll
        for (int nt = 0; nt < 4; ++nt) acc[m][nt] = (float4v){0.f, 0.f, 0.f, 0.f};

    {
        const unsigned short* aptr = wf + (((size_t)(cohalf * 2) * 64 + lane) << 3);
        CONV_GEMM(aptr, acc, s_b2[0]);
    }

    float fpv[2][4][4];
#pragma unroll
    for (int m = 0; m < 2; ++m) {
        const int mt  = cohalf * 2 + m;
        const int co0 = mt * 16 + quad * 4;
        float4 bv = *(const float4*)&bf[co0];
#pragma unroll
        for (int nt = 0; nt < 4; ++nt) {
            fpv[m][nt][0] = bulo((unsigned int)f2bu(acc[m][nt][0] + bv.x));
            fpv[m][nt][1] = bulo((unsigned int)f2bu(acc[m][nt][1] + bv.y));
            fpv[m][nt][2] = bulo((unsigned int)f2bu(acc[m][nt][2] + bv.z));
            fpv[m][nt][3] = bulo((unsigned int)f2bu(acc[m][nt][3] + bv.w));
        }
    }

#pragma unroll
    for (int m = 0; m < 2; ++m)
#pragma unroll
        for (int nt = 0; nt < 4; ++nt) acc[m][nt] = (float4v){0.f, 0.f, 0.f, 0.f};

    {
        const unsigned short* aptr = wm + (((size_t)(cohalf * 2) * 64 + lane) << 3);
        CONV_GEMM(aptr, acc, s_b2[1]);
    }

    const int h = h0 + rowsel;
#pragma unroll
    for (int m = 0; m < 2; ++m) {
        const int mt  = cohalf * 2 + m;
        const int co0 = mt * 16 + quad * 4;
        float4 bv = *(const float4*)&bm[co0];
#pragma unroll
        for (int nt = 0; nt < 4; ++nt) {
            const int px = h * Wc + w0 + nt * 16 + n15;
            float v[4] = {acc[m][nt][0] + bv.x, acc[m][nt][1] + bv.y,
                          acc[m][nt][2] + bv.z, acc[m][nt][3] + bv.w};
#pragma unroll
            for (int r = 0; r < 4; ++r)
                featp[((size_t)b * Cc + co0 + r) * HWc + px] =
                    f2bu(v[r] * fpv[m][nt][r]);
        }
    }
}

// ---------------------------------------------------------------------------
// Dynamic local 7x7 conv + residual (round-14/16 version, unchanged).
// ---------------------------------------------------------------------------
__global__ __launch_bounds__(256) void local_conv_v4(
    const float* __restrict__ x, const unsigned short* __restrict__ featp,
    const unsigned short* __restrict__ lp, float* __restrict__ out)
{
    const int tid  = threadIdx.x;
    const int glin = blockIdx.x;
    const int xcd  = glin & 7;
    const int slot = glin >> 3;              // 0..127
    const int pair = xcd * 8 + (slot >> 4);  // 0..63
    const int cg   = slot & 15;
    const int b    = pair >> 4;
    const int hti  = pair & 15;

    const int w4  = (tid & 31) * 4;
    const int ro  = tid >> 5;
    const int h   = hti * 8 + ro;
    const int c0  = cg * 4;

    float msk[12];
#pragma unroll
    for (int e = 0; e < 12; ++e) {
        int gw = w4 - 4 + e;
        msk[e] = ((unsigned)gw < (unsigned)Wc) ? 1.f : 0.f;
    }

    float acc[4][4];
#pragma unroll
    for (int ch = 0; ch < 4; ++ch)
#pragma unroll
        for (int p = 0; p < 4; ++p) acc[ch][p] = 0.f;

    const unsigned short* lpb = lp + (size_t)b * 49 * HWc + (size_t)h * Wc + w4;
    const unsigned short* fb  = featp + ((size_t)b * Cc + c0) * HWc;

#pragma unroll
    for (int dy = 0; dy < 7; ++dy) {
        const int gh = h + dy - 3;
        if ((unsigned)gh >= (unsigned)Hc) continue;

        float lpf[7][4];
#pragma unroll
        for (int dx = 0; dx < 7; ++dx) {
            uint2 lv = *(const uint2*)&lpb[(size_t)(dy * 7 + dx) * HWc];
            lpf[dx][0] = bulo(lv.x); lpf[dx][1] = buhi(lv.x);
            lpf[dx][2] = bulo(lv.y); lpf[dx][3] = buhi(lv.y);
        }

        const unsigned short* frow = fb + (size_t)gh * Wc + w4;
#pragma unroll
        for (int ch = 0; ch < 4; ++ch) {
            const unsigned short* fr = frow + (size_t)ch * HWc;
            uint2 a  = *(const uint2*)(fr - 4);
            uint2 bq = *(const uint2*)(fr);
            uint2 cq = *(const uint2*)(fr + 4);
            float f[12];
            f[0]  = bulo(a.x);             f[1]  = buhi(a.x) * msk[1];
            f[2]  = bulo(a.y) * msk[2];    f[3]  = buhi(a.y) * msk[3];
            f[4]  = bulo(bq.x);            f[5]  = buhi(bq.x);
            f[6]  = bulo(bq.y);            f[7]  = buhi(bq.y);
            f[8]  = bulo(cq.x) * msk[8];   f[9]  = buhi(cq.x) * msk[9];
            f[10] = bulo(cq.y) * msk[10];  f[11] = buhi(cq.y);
#pragma unroll
            for (int dx = 0; dx < 7; ++dx)
#pragma unroll
                for (int p = 0; p < 4; ++p)
                    acc[ch][p] = fmaf(f[p + dx + 1], lpf[dx][p], acc[ch][p]);
        }
    }

#pragma unroll
    for (int ch = 0; ch < 4; ++ch) {
        const size_t idx = ((size_t)b * Cc + c0 + ch) * HWc + (size_t)h * Wc + w4;
        float4 xv = *(const float4*)&x[idx];
        float4 r  = {acc[ch][0] + xv.x, acc[ch][1] + xv.y,
                     acc[ch][2] + xv.z, acc[ch][3] + xv.w};
        *(float4*)&out[idx] = r;
    }
}

// ---------------------------------------------------------------------------
extern "C" void kernel_launch(void* const* d_in, const int* in_sizes, int n_in,
                              void* d_out, int out_size, void* d_ws, size_t ws_size,
                              hipStream_t stream)
{
    const float* x   = (const float*)d_in[0];
    const float* kf  = (const float*)d_in[1];
    const float* fw1 = (const float*)d_in[2];
    const float* fb1 = (const float*)d_in[3];
    const float* fw2 = (const float*)d_in[4];
    const float* fb2 = (const float*)d_in[5];
    const float* mw1 = (const float*)d_in[6];
    const float* mb1 = (const float*)d_in[7];
    const float* mw2 = (const float*)d_in[8];
    const float* mb2 = (const float*)d_in[9];
    const float* lw1 = (const float*)d_in[10];
    const float* lb1 = (const float*)d_in[11];
    const float* lw2 = (const float*)d_in[12];
    const float* lb2 = (const float*)d_in[13];

    float* out = (float*)d_out;
    char*  ws  = (char*)d_ws;

    const size_t NBH = (size_t)Bc * HWc * Cc * 2;   // bf16 tensor: 8.4 MB
    const size_t LPH = (size_t)Bc * 49 * HWc * 2;   // bf16 lp planes: 6.4 MB
    const size_t WBA = (size_t)(4 * 36864 + 2 * 4096) * 2;

    unsigned short* t1f   = (unsigned short*)(ws);
    unsigned short* t1m   = (unsigned short*)(ws + NBH);
    unsigned short* featp = (unsigned short*)(ws + 2 * NBH);
    unsigned short* lpb   = (unsigned short*)(ws + 3 * NBH);
    unsigned short* xb    = (unsigned short*)(ws + 3 * NBH + LPH);
    unsigned short* kfb   = (unsigned short*)((char*)xb + NBH);
    unsigned short* wbase = (unsigned short*)((char*)kfb + NBH);
    unsigned short* zpage = (unsigned short*)((char*)wbase + WBA);
    unsigned short* wb1   = wbase;
    unsigned short* wb2   = wbase + 36864;
    unsigned short* wb3   = wbase + 2 * 36864;
    unsigned short* wb4   = wbase + 3 * 36864;
    unsigned short* wl1   = wbase + 4 * 36864;
    unsigned short* wl2   = wbase + 4 * 36864 + 4096;

    dim3 blk(256);

    prep_k<<<dim3(589), blk, 0, stream>>>(x, kf, fw1, fw2, mw1, mw2, lw1, lw2,
                                          xb, kfb, wbase, zpage);

    conv1_lp_k<<<dim3(2048), blk, 0, stream>>>(xb, kfb, wb1, wb3, fb1, mb1, zpage,
                                               t1f, t1m, wl1, lb1, wl2, lb2, lpb);

    conv2_fused_k<<<dim3(512), blk, 0, stream>>>(t1f, t1m, wb2, wb4, fb2, mb2,
                                                 zpage, featp);

    local_conv_v4<<<dim3(1024), blk, 0, stream>>>(x, featp, lpb, out);
}